// Round 20
// baseline (225.303 us; speedup 1.0000x reference)
//
#include <hip/hip_runtime.h>
#include <hip/hip_fp16.h>
#include <math.h>

#define N_NODES 10000
#define N_EDGES 160000
#define NAG     5000
#define HC      1024     // H*C_HID
#define CH      128
#define NEG     0.2f
#define BCAP    64       // bucket capacity (max deg+self ~41 for this dataset)

#define NSCAT   625      // 160000/256
#define NGEMM   1256     // 157*8
#define GATB1   512      // gat1 block-groups (x8 heads = 4096 blocks, x4 waves = 2048 streams)
#define GATB2   256      // gat2 block-groups

typedef _Float16 f16x8 __attribute__((ext_vector_type(8)));
typedef _Float16 f16x2 __attribute__((ext_vector_type(2)));
typedef float f32x4 __attribute__((ext_vector_type(4)));

// ======================= shared device helpers =======================
__device__ __forceinline__ __half2 pk_max(__half2 a, __half2 b) {
    __half2 r;
    asm volatile("v_pk_max_f16 %0, %1, %2" : "=v"(r) : "v"(a), "v"(b));
    return r;
}

// per-edge: score partial over this thread's 8 channels, 16-lane reduce, exp,
// accumulate via v_fma_mix (fp16 src, fp32 acc - exact fp32 accumulate).
__device__ __forceinline__ void edge_accum(float4 raw, const __half2* xr2, const __half2* att2,
                                           float& lsum, float* acc, bool valid) {
    __half2* hp = (__half2*)&raw;
    const __half2 neg2 = __float2half2_rn(NEG);
    float p = 0.f;
    #pragma unroll
    for (int j = 0; j < 4; j++) {
        __half2 z = __hadd2(hp[j], xr2[j]);
        __half2 lz = pk_max(z, __hmul2(z, neg2));
#if __has_builtin(__builtin_amdgcn_fdot2)
        p = __builtin_amdgcn_fdot2(*(f16x2*)&lz, *(const f16x2*)&att2[j], p, false);
#else
        float2 lf = __half22float2(lz);
        float2 af = __half22float2(att2[j]);
        p = fmaf(lf.x, af.x, p);
        p = fmaf(lf.y, af.y, p);
#endif
    }
    p += __shfl_xor(p, 1, 64);
    p += __shfl_xor(p, 2, 64);
    p += __shfl_xor(p, 4, 64);
    p += __shfl_xor(p, 8, 64);
    float w = valid ? __expf(p) : 0.f;
    lsum += w;
    #pragma unroll
    for (int j = 0; j < 4; j++) {
        asm("v_fma_mix_f32 %0, %1, %2, %0 op_sel_hi:[1,0,0]"
            : "+v"(acc[2 * j]) : "v"(hp[j]), "v"(w));
        asm("v_fma_mix_f32 %0, %1, %2, %0 op_sel:[1,0,0] op_sel_hi:[1,0,0]"
            : "+v"(acc[2 * j + 1]) : "v"(hp[j]), "v"(w));
    }
}

// ---- single MFMA GEMM tile: 64 rows x 256 cols; outputs fp16 both sides ----
// W pre-packed in MFMA-fragment order (frag = kq*64 + col_tile, 1 KB each).
template <int K, int KA, typename AT>
__device__ void gemm_tile(char* smem, int vt,
                          const AT* __restrict__ A,
                          const _Float16* __restrict__ Whl, const float* __restrict__ bl,
                          const _Float16* __restrict__ Whr, const float* __restrict__ br,
                          _Float16* __restrict__ xl, _Float16* __restrict__ xr,
                          int limitL, int limitR) {
    _Float16* ash = (_Float16*)smem;
    float (*eps)[68] = (float(*)[68])smem;
    __shared__ float bsh[256];
    const int AS = K + 8;
    int by = vt & 7;
    int rowblk = (vt >> 3) * 64;
    bool right = by >= 4;
    if (rowblk >= (right ? limitR : limitL)) return;
    const _Float16* Wh = right ? Whr : Whl;
    const float* bs    = right ? br : bl;
    _Float16* outp     = right ? xr : xl;
    int colbase = (by & 3) * 256;
    int t = threadIdx.x;
    int w = t >> 6, l = t & 63;
    int m = l & 15, q = l >> 4;

    bsh[t] = bs[colbase + t];   // coalesced bias load; covered by staging sync
    for (int idx = t; idx < 64 * (K / 8); idx += 256) {
        int r  = idx / (K / 8);
        int c8 = (idx % (K / 8)) * 8;
        int row = rowblk + r;
        f16x8 hv = (f16x8){0, 0, 0, 0, 0, 0, 0, 0};
        if (row < N_NODES && c8 < KA) {
            if constexpr (sizeof(AT) == 2) {
                hv = *(const f16x8*)((const _Float16*)A + (size_t)row * KA + c8);
            } else {
                float4 v0 = *(const float4*)((const float*)A + (size_t)row * KA + c8);
                float4 v1 = *(const float4*)((const float*)A + (size_t)row * KA + c8 + 4);
                hv[0] = (_Float16)v0.x; hv[1] = (_Float16)v0.y; hv[2] = (_Float16)v0.z; hv[3] = (_Float16)v0.w;
                hv[4] = (_Float16)v1.x; hv[5] = (_Float16)v1.y; hv[6] = (_Float16)v1.z; hv[7] = (_Float16)v1.w;
            }
        }
        *(f16x8*)&ash[r * AS + c8] = hv;
    }
    __syncthreads();

    f32x4 acc[16];
    #pragma unroll
    for (int i = 0; i < 16; i++) acc[i] = (f32x4){0.f, 0.f, 0.f, 0.f};

    #pragma unroll
    for (int kq = 0; kq < K / 32; kq++) {
        f16x8 af = *(const f16x8*)&ash[(w * 16 + m) * AS + kq * 32 + q * 8];
        const _Float16* base = Wh + (((size_t)(kq * 64 + (colbase >> 4))) << 9) + l * 8;
        #pragma unroll
        for (int tile = 0; tile < 16; tile++) {
            f16x8 bf = *(const f16x8*)(base + ((size_t)tile << 9));
            acc[tile] = __builtin_amdgcn_mfma_f32_16x16x32_f16(af, bf, acc[tile], 0, 0, 0);
        }
    }

    float bv[16];
    #pragma unroll
    for (int tile = 0; tile < 16; tile++) bv[tile] = bsh[tile * 16 + m];

    for (int cgk = 0; cgk < 4; cgk++) {
        __syncthreads();
        #pragma unroll
        for (int tt = 0; tt < 4; tt++) {
            int tile = cgk * 4 + tt;
            int cl = tt * 16 + m;
            #pragma unroll
            for (int reg = 0; reg < 4; reg++)
                eps[w * 16 + q * 4 + reg][cl] = acc[tile][reg] + bv[tile];
        }
        __syncthreads();
        int colg = colbase + cgk * 64;
        int cc = (t & 15) * 4;
        #pragma unroll
        for (int it = 0; it < 4; it++) {
            int r = it * 16 + (t >> 4);
            int row = rowblk + r;
            if (row < N_NODES) {
                float4 v = *(const float4*)&eps[r][cc];
                __half2 h01 = __floats2half2_rn(v.x, v.y);
                __half2 h23 = __floats2half2_rn(v.z, v.w);
                float2 st;
                st.x = *(float*)&h01;
                st.y = *(float*)&h23;
                *(float2*)(outp + (size_t)row * HC + colg + cc) = st;
            }
        }
    }
}

// ======================= per-(dst,head) GAT: 4 independent waves per block ==========
// head = blockIdx & 7 -> round-robin block->XCD keeps each XCD's L2 on one 2.56 MB
// head slice. Each wave (t>>6) owns its dst stream: no LDS, no syncthreads.
__global__ __launch_bounds__(256) void gat_kernel(const __half* __restrict__ xl,
                                                  const _Float16* __restrict__ xr,
                                                  const float* __restrict__ att,
                                                  const int* __restrict__ cnt,
                                                  const int* __restrict__ srcs,
                                                  _Float16* __restrict__ hpart,
                                                  int ngroups, int ndst) {
    int b = blockIdx.x;
    int head = b & 7;
    int wave = threadIdx.x >> 6;
    int g = (b >> 3) * 4 + wave;
    int nstreams = ngroups * 4;
    int t = threadIdx.x & 63;
    int slot = t >> 4, l16 = t & 15;
    int ch0 = head * CH + l16 * 8;

    __half2 att2[4];
    {
        float4 b0 = *(const float4*)(att + ch0);
        float4 b1 = *(const float4*)(att + ch0 + 4);
        att2[0] = __floats2half2_rn(b0.x, b0.y);
        att2[1] = __floats2half2_rn(b0.z, b0.w);
        att2[2] = __floats2half2_rn(b1.x, b1.y);
        att2[3] = __floats2half2_rn(b1.z, b1.w);
    }

    for (int dst = g; dst < ndst; dst += nstreams) {
        __half2 xr2[4];
        {
            f16x8 xv = *(const f16x8*)(xr + (size_t)dst * HC + ch0);
            __half2* xp = (__half2*)&xv;
            xr2[0] = xp[0]; xr2[1] = xp[1]; xr2[2] = xp[2]; xr2[3] = xp[3];
        }

        float acc[8];
        #pragma unroll
        for (int j = 0; j < 8; j++) acc[j] = 0.f;
        float lsum = 0.f;

        int e0 = dst << 6;
        int e1 = e0 + cnt[dst];
        for (int base = e0; base < e1; base += 4) {   // wave-uniform bound
            int ee = base + slot;
            bool valid = ee < e1;
            int s = srcs[valid ? ee : e0];
            float4 raw = *(const float4*)(xl + (size_t)s * HC + ch0);
            edge_accum(raw, xr2, att2, lsum, acc, valid);
        }

        // reduce across the 4 slot groups (lanes +-16, +-32)
        #pragma unroll
        for (int j = 0; j < 8; j++) {
            acc[j] += __shfl_xor(acc[j], 16, 64);
            acc[j] += __shfl_xor(acc[j], 32, 64);
        }
        lsum += __shfl_xor(lsum, 16, 64);
        lsum += __shfl_xor(lsum, 32, 64);

        if (t < 16) {
            float inv = 1.f / (lsum + 1e-16f);
            f16x8 hv;
            #pragma unroll
            for (int j = 0; j < 8; j++) hv[j] = (_Float16)(acc[j] * inv);
            *(f16x8*)(hpart + (size_t)dst * HC + head * CH + l16 * 8) = hv;
        }
    }
}

// ======================= D3.5: fold hp1 -> h1c = relu(0.125*sum_heads + b1) ==========
__global__ __launch_bounds__(256) void fold_kernel(const _Float16* __restrict__ hpart,
                                                   const float* __restrict__ b1,
                                                   _Float16* __restrict__ h1c) {
    int t = threadIdx.x;
    int row = blockIdx.x * 16 + (t >> 4);
    int ch0 = (t & 15) * 8;
    if (row >= N_NODES) return;
    f16x8 hvv[8];
    #pragma unroll
    for (int h = 0; h < 8; h++)
        hvv[h] = *(const f16x8*)(hpart + (size_t)row * HC + h * CH + ch0);
    float4 bb0 = *(const float4*)(b1 + ch0);
    float4 bb1 = *(const float4*)(b1 + ch0 + 4);
    float tb[8] = {bb0.x, bb0.y, bb0.z, bb0.w, bb1.x, bb1.y, bb1.z, bb1.w};
    f16x8 o;
    #pragma unroll
    for (int j = 0; j < 8; j++) {
        float s = 0.f;
        #pragma unroll
        for (int h = 0; h < 8; h++) s += (float)hvv[h][j];
        o[j] = (_Float16)fmaxf(fmaf(s, 0.125f, tb[j]), 0.f);
    }
    *(f16x8*)(h1c + (size_t)row * CH + ch0) = o;
}

// ======================= D6: head-mean + relu + final linear =======================
__global__ __launch_bounds__(256) void out_kernel(const _Float16* __restrict__ hpart2,
                                                  const float* __restrict__ b2,
                                                  const float* __restrict__ Wlin,
                                                  const float* __restrict__ blin,
                                                  float* __restrict__ out) {
    int dst = blockIdx.x;
    int t = threadIdx.x;
    __shared__ float hrow[CH];
    if (t < 128) {
        float s = 0.f;
        #pragma unroll
        for (int h = 0; h < 8; h++) s += (float)hpart2[(size_t)dst * HC + h * CH + t];
        hrow[t] = fmaxf(fmaf(s, 0.125f, b2[t]), 0.f);
    }
    __syncthreads();
    if (t < 64) {
        int j = t & 7, p8 = t >> 3;
        float v = 0.f;
        #pragma unroll
        for (int kk = 0; kk < 16; kk++) {
            int k = p8 * 16 + kk;
            v = fmaf(hrow[k], Wlin[k * 8 + j], v);
        }
        v += __shfl_xor(v, 8, 64);
        v += __shfl_xor(v, 16, 64);
        v += __shfl_xor(v, 32, 64);
        if (t < 8) out[(size_t)dst * 8 + t] = v + blin[t];
    }
}

// ======================= fragment-order W conversion (per-thread 16 B chunk) ==========
__device__ __forceinline__ void emit_frag8(const float* __restrict__ W, _Float16* __restrict__ o,
                                           int tid, int KAreal) {
    int f = tid >> 6, l = tid & 63;
    int kq = f >> 6, tile = f & 63;
    int m = l & 15, q = l >> 4;
    int col = tile * 16 + m;
    float v[8];
    #pragma unroll
    for (int j = 0; j < 8; j++) {
        int k = kq * 32 + q * 8 + j;
        v[j] = (k < KAreal) ? W[k * 1024 + col] : 0.f;
    }
    f16x8 hv;
    #pragma unroll
    for (int j = 0; j < 8; j++) hv[j] = (_Float16)v[j];
    *(f16x8*)(o + ((size_t)tid << 3)) = hv;
}

// ======================= D1: init buckets + convert w1 & w2 =======================
__global__ __launch_bounds__(256) void prep_kernel(const float* __restrict__ Wl1, const float* __restrict__ Wr1,
                                                   const float* __restrict__ Wl2, const float* __restrict__ Wr2,
                                                   _Float16* __restrict__ w1l, _Float16* __restrict__ w1r,
                                                   _Float16* __restrict__ w2l, _Float16* __restrict__ w2r,
                                                   int* __restrict__ cnt, int* __restrict__ srcs) {
    int t = threadIdx.x;
    int b = blockIdx.x;
    if (b < 40) {
        int i = b * 256 + t;
        if (i < N_NODES) {
            cnt[i] = 1;               // self loop pre-seeded
            srcs[i << 6] = i;
        }
        return;
    }
    if (b < 72) {
        int tid = (b - 40) * 256 + t;       // 8192 chunks: 4096 per side
        if (tid < 4096) emit_frag8(Wl1, w1l, tid, 16);
        else            emit_frag8(Wr1, w1r, tid - 4096, 16);
        return;
    }
    int tid = (b - 72) * 256 + t;           // 32768 chunks: 16384 per side
    if (tid < 16384) emit_frag8(Wl2, w2l, tid, 128);
    else             emit_frag8(Wr2, w2r, tid - 16384, 128);
}

// ======================= D2: gemm1 ∥ scatter =======================
__global__ __launch_bounds__(256) void d2_kernel(const int* __restrict__ esrc,
                                                 const int* __restrict__ edst,
                                                 int* __restrict__ cnt,
                                                 int* __restrict__ srcs,
                                                 const float* __restrict__ x,
                                                 const _Float16* __restrict__ w1l, const float* __restrict__ bl1,
                                                 const _Float16* __restrict__ w1r, const float* __restrict__ br1,
                                                 _Float16* __restrict__ xlh, _Float16* __restrict__ xrh) {
    __shared__ __align__(16) char smem[17408];
    int b = blockIdx.x;
    if (b < NGEMM) {
        gemm_tile<32, 16, float>(smem, b, x, w1l, bl1, w1r, br1,
                                 xlh, xrh, N_NODES, N_NODES);
    } else {
        int e = (b - NGEMM) * 256 + threadIdx.x;   // NSCAT*256 == N_EDGES
        int d = edst[e];
        int p = atomicAdd(&cnt[d], 1);
        if (p < BCAP) srcs[(d << 6) + p] = esrc[e];
    }
}

// ======================= D4: gemm2 (A = folded fp16 h1c) =======================
__global__ __launch_bounds__(256) void gemm2_kernel(const _Float16* __restrict__ h1c,
                                                    const _Float16* __restrict__ w2l, const float* __restrict__ bl2,
                                                    const _Float16* __restrict__ w2r, const float* __restrict__ br2,
                                                    _Float16* __restrict__ xlh, _Float16* __restrict__ xrh) {
    __shared__ __align__(16) char smem[17408];
    gemm_tile<128, 128, _Float16>(smem, blockIdx.x, h1c, w2l, bl2, w2r, br2,
                                  xlh, xrh, N_NODES, NAG);
}

extern "C" void kernel_launch(void* const* d_in, const int* in_sizes, int n_in,
                              void* d_out, int out_size, void* d_ws, size_t ws_size,
                              hipStream_t stream) {
    const float* x    = (const float*)d_in[0];
    const int*   ei   = (const int*)d_in[1];
    const float* Wl1  = (const float*)d_in[2];
    const float* bl1  = (const float*)d_in[3];
    const float* Wr1  = (const float*)d_in[4];
    const float* br1  = (const float*)d_in[5];
    const float* att1 = (const float*)d_in[6];
    const float* b1   = (const float*)d_in[7];
    const float* Wl2  = (const float*)d_in[8];
    const float* bl2  = (const float*)d_in[9];
    const float* Wr2  = (const float*)d_in[10];
    const float* br2  = (const float*)d_in[11];
    const float* att2 = (const float*)d_in[12];
    const float* b2   = (const float*)d_in[13];
    const float* Wlin = (const float*)d_in[14];
    const float* blin = (const float*)d_in[15];
    float* out = (float*)d_out;

    const int* esrc = ei;
    const int* edst = ei + N_EDGES;

    char* p = (char*)d_ws;
    __half* xlh    = (__half*)p;               p += (size_t)N_NODES * HC * sizeof(__half);
    _Float16* xrh  = (_Float16*)p;             p += (size_t)N_NODES * HC * sizeof(_Float16);
    _Float16* hp1  = (_Float16*)p;             p += (size_t)N_NODES * HC * sizeof(_Float16);
    _Float16* hp2  = (_Float16*)p;             p += (size_t)NAG * HC * sizeof(_Float16);
    _Float16* h1c  = (_Float16*)p;             p += (size_t)N_NODES * CH * sizeof(_Float16);
    _Float16* w1l = (_Float16*)p;              p += 1024 * 32 * sizeof(_Float16);
    _Float16* w1r = (_Float16*)p;              p += 1024 * 32 * sizeof(_Float16);
    _Float16* w2l = (_Float16*)p;              p += 1024 * 128 * sizeof(_Float16);
    _Float16* w2r = (_Float16*)p;              p += 1024 * 128 * sizeof(_Float16);
    int* cnt  = (int*)p;                       p += (size_t)N_NODES * sizeof(int) + 64;
    int* srcs = (int*)p;                       // N_NODES * BCAP

    // D1: init buckets (self-loops) + convert w1/w2 to fragment order
    prep_kernel<<<200, 256, 0, stream>>>(Wl1, Wr1, Wl2, Wr2, w1l, w1r, w2l, w2r, cnt, srcs);
    // D2: layer-1 GEMM ∥ bucket scatter
    d2_kernel<<<NGEMM + NSCAT, 256, 0, stream>>>(esrc, edst, cnt, srcs, x,
                                                 w1l, bl1, w1r, br1,
                                                 (_Float16*)xlh, xrh);
    // D3: layer-1 GAT, 4 waves/block; head = blockIdx&7 -> XCD slicing
    gat_kernel<<<GATB1 * 8, 256, 0, stream>>>(xlh, xrh, att1, cnt, srcs, hp1,
                                              GATB1, N_NODES);
    // D3.5: fold heads -> h1c (relu + b1)
    fold_kernel<<<(N_NODES + 15) / 16, 256, 0, stream>>>(hp1, b1, h1c);
    // D4: layer-2 GEMM (plain fp16 A)
    gemm2_kernel<<<NGEMM, 256, 0, stream>>>(h1c, w2l, bl2, w2r, br2,
                                            (_Float16*)xlh, xrh);
    // D5: layer-2 GAT (drone dsts only)
    gat_kernel<<<GATB2 * 8, 256, 0, stream>>>(xlh, xrh, att2, cnt, srcs, hp2,
                                              GATB2, NAG);
    // D6: head-mean + relu + b2 + final linear
    out_kernel<<<NAG, 256, 0, stream>>>(hp2, b2, Wlin, blin, out);
}

// Round 21
// 216.271 us; speedup vs baseline: 1.0418x; 1.0418x over previous
//
#include <hip/hip_runtime.h>
#include <hip/hip_fp16.h>
#include <math.h>

#define N_NODES 10000
#define N_EDGES 160000
#define NAG     5000
#define HC      1024     // H*C_HID
#define CH      128
#define NEG     0.2f
#define BCAP    64       // bucket capacity (max deg+self ~41 for this dataset)

#define NSCAT   625      // 160000/256
#define NGEMM   1256     // 157*8
#define GATG1   2048     // dst groups for gat1 (x8 heads = 16384 blocks)
#define GATG2   1024     // dst groups for gat2

typedef _Float16 f16x8 __attribute__((ext_vector_type(8)));
typedef _Float16 f16x2 __attribute__((ext_vector_type(2)));
typedef float f32x4 __attribute__((ext_vector_type(4)));

// ======================= shared device helpers =======================
__device__ __forceinline__ __half2 pk_max(__half2 a, __half2 b) {
    __half2 r;
    asm volatile("v_pk_max_f16 %0, %1, %2" : "=v"(r) : "v"(a), "v"(b));
    return r;
}

// per-edge: score partial over this thread's 8 channels, 16-lane reduce, exp,
// accumulate via v_fma_mix (fp16 src, fp32 acc - exact fp32 accumulate).
__device__ __forceinline__ void edge_accum(float4 raw, const __half2* xr2, const __half2* att2,
                                           float& lsum, float* acc, bool valid) {
    __half2* hp = (__half2*)&raw;
    const __half2 neg2 = __float2half2_rn(NEG);
    float p = 0.f;
    #pragma unroll
    for (int j = 0; j < 4; j++) {
        __half2 z = __hadd2(hp[j], xr2[j]);
        __half2 lz = pk_max(z, __hmul2(z, neg2));
#if __has_builtin(__builtin_amdgcn_fdot2)
        p = __builtin_amdgcn_fdot2(*(f16x2*)&lz, *(const f16x2*)&att2[j], p, false);
#else
        float2 lf = __half22float2(lz);
        float2 af = __half22float2(att2[j]);
        p = fmaf(lf.x, af.x, p);
        p = fmaf(lf.y, af.y, p);
#endif
    }
    p += __shfl_xor(p, 1, 64);
    p += __shfl_xor(p, 2, 64);
    p += __shfl_xor(p, 4, 64);
    p += __shfl_xor(p, 8, 64);
    float w = valid ? __expf(p) : 0.f;
    lsum += w;
    #pragma unroll
    for (int j = 0; j < 4; j++) {
        asm("v_fma_mix_f32 %0, %1, %2, %0 op_sel_hi:[1,0,0]"
            : "+v"(acc[2 * j]) : "v"(hp[j]), "v"(w));
        asm("v_fma_mix_f32 %0, %1, %2, %0 op_sel:[1,0,0] op_sel_hi:[1,0,0]"
            : "+v"(acc[2 * j + 1]) : "v"(hp[j]), "v"(w));
    }
}

// ---- single MFMA GEMM tile: 64 rows x 256 cols; outputs fp16 both sides ----
// W pre-packed in MFMA-fragment order (frag = kq*64 + col_tile, 1 KB each).
template <int K, int KA, typename AT>
__device__ void gemm_tile(char* smem, int vt,
                          const AT* __restrict__ A,
                          const _Float16* __restrict__ Whl, const float* __restrict__ bl,
                          const _Float16* __restrict__ Whr, const float* __restrict__ br,
                          _Float16* __restrict__ xl, _Float16* __restrict__ xr,
                          int limitL, int limitR) {
    _Float16* ash = (_Float16*)smem;
    float (*eps)[68] = (float(*)[68])smem;
    __shared__ float bsh[256];
    const int AS = K + 8;
    int by = vt & 7;
    int rowblk = (vt >> 3) * 64;
    bool right = by >= 4;
    if (rowblk >= (right ? limitR : limitL)) return;
    const _Float16* Wh = right ? Whr : Whl;
    const float* bs    = right ? br : bl;
    _Float16* outp     = right ? xr : xl;
    int colbase = (by & 3) * 256;
    int t = threadIdx.x;
    int w = t >> 6, l = t & 63;
    int m = l & 15, q = l >> 4;

    bsh[t] = bs[colbase + t];   // coalesced bias load; covered by staging sync
    for (int idx = t; idx < 64 * (K / 8); idx += 256) {
        int r  = idx / (K / 8);
        int c8 = (idx % (K / 8)) * 8;
        int row = rowblk + r;
        f16x8 hv = (f16x8){0, 0, 0, 0, 0, 0, 0, 0};
        if (row < N_NODES && c8 < KA) {
            if constexpr (sizeof(AT) == 2) {
                hv = *(const f16x8*)((const _Float16*)A + (size_t)row * KA + c8);
            } else {
                float4 v0 = *(const float4*)((const float*)A + (size_t)row * KA + c8);
                float4 v1 = *(const float4*)((const float*)A + (size_t)row * KA + c8 + 4);
                hv[0] = (_Float16)v0.x; hv[1] = (_Float16)v0.y; hv[2] = (_Float16)v0.z; hv[3] = (_Float16)v0.w;
                hv[4] = (_Float16)v1.x; hv[5] = (_Float16)v1.y; hv[6] = (_Float16)v1.z; hv[7] = (_Float16)v1.w;
            }
        }
        *(f16x8*)&ash[r * AS + c8] = hv;
    }
    __syncthreads();

    f32x4 acc[16];
    #pragma unroll
    for (int i = 0; i < 16; i++) acc[i] = (f32x4){0.f, 0.f, 0.f, 0.f};

    #pragma unroll
    for (int kq = 0; kq < K / 32; kq++) {
        f16x8 af = *(const f16x8*)&ash[(w * 16 + m) * AS + kq * 32 + q * 8];
        const _Float16* base = Wh + (((size_t)(kq * 64 + (colbase >> 4))) << 9) + l * 8;
        #pragma unroll
        for (int tile = 0; tile < 16; tile++) {
            f16x8 bf = *(const f16x8*)(base + ((size_t)tile << 9));
            acc[tile] = __builtin_amdgcn_mfma_f32_16x16x32_f16(af, bf, acc[tile], 0, 0, 0);
        }
    }

    float bv[16];
    #pragma unroll
    for (int tile = 0; tile < 16; tile++) bv[tile] = bsh[tile * 16 + m];

    for (int cgk = 0; cgk < 4; cgk++) {
        __syncthreads();
        #pragma unroll
        for (int tt = 0; tt < 4; tt++) {
            int tile = cgk * 4 + tt;
            int cl = tt * 16 + m;
            #pragma unroll
            for (int reg = 0; reg < 4; reg++)
                eps[w * 16 + q * 4 + reg][cl] = acc[tile][reg] + bv[tile];
        }
        __syncthreads();
        int colg = colbase + cgk * 64;
        int cc = (t & 15) * 4;
        #pragma unroll
        for (int it = 0; it < 4; it++) {
            int r = it * 16 + (t >> 4);
            int row = rowblk + r;
            if (row < N_NODES) {
                float4 v = *(const float4*)&eps[r][cc];
                __half2 h01 = __floats2half2_rn(v.x, v.y);
                __half2 h23 = __floats2half2_rn(v.z, v.w);
                float2 st;
                st.x = *(float*)&h01;
                st.y = *(float*)&h23;
                *(float2*)(outp + (size_t)row * HC + colg + cc) = st;
            }
        }
    }
}

// ======================= per-(dst,head) GAT: one wave per block =======================
// head = blockIdx & 7 -> round-robin block->XCD keeps each XCD's L2 on one 2.56 MB
// head slice. Bucket indices prefetched in ONE coalesced load (lane t = srcs[e0+t]);
// per-iteration index via __shfl (ds_bpermute) - removes a global load + vmcnt wait
// from every iteration's dependent chain.
__global__ __launch_bounds__(64) void gat_kernel(const __half* __restrict__ xl,
                                                 const _Float16* __restrict__ xr,
                                                 const float* __restrict__ att,
                                                 const int* __restrict__ cnt,
                                                 const int* __restrict__ srcs,
                                                 _Float16* __restrict__ hpart,
                                                 int ngroups, int ndst) {
    int b = blockIdx.x;
    int g = b >> 3, head = b & 7;
    int t = threadIdx.x;
    int slot = t >> 4, l16 = t & 15;
    int ch0 = head * CH + l16 * 8;

    __half2 att2[4];
    {
        float4 b0 = *(const float4*)(att + ch0);
        float4 b1 = *(const float4*)(att + ch0 + 4);
        att2[0] = __floats2half2_rn(b0.x, b0.y);
        att2[1] = __floats2half2_rn(b0.z, b0.w);
        att2[2] = __floats2half2_rn(b1.x, b1.y);
        att2[3] = __floats2half2_rn(b1.z, b1.w);
    }

    for (int dst = g; dst < ndst; dst += ngroups) {
        int e0 = dst << 6;
        int sidx = srcs[e0 + t];          // one coalesced 256 B load: whole bucket
        int c = cnt[dst];
        c = c < BCAP ? c : BCAP;

        __half2 xr2[4];
        {
            f16x8 xv = *(const f16x8*)(xr + (size_t)dst * HC + ch0);
            __half2* xp = (__half2*)&xv;
            xr2[0] = xp[0]; xr2[1] = xp[1]; xr2[2] = xp[2]; xr2[3] = xp[3];
        }

        float acc[8];
        #pragma unroll
        for (int j = 0; j < 8; j++) acc[j] = 0.f;
        float lsum = 0.f;

        for (int base = 0; base < c; base += 4) {   // wave-uniform bound
            int ee = base + slot;
            bool valid = ee < c;
            int s = __shfl(sidx, ee, 64);           // ds_bpermute: short-latency index fetch
            s = valid ? s : dst;
            float4 raw = *(const float4*)(xl + (size_t)s * HC + ch0);
            edge_accum(raw, xr2, att2, lsum, acc, valid);
        }

        // reduce across the 4 slot groups (lanes +-16, +-32)
        #pragma unroll
        for (int j = 0; j < 8; j++) {
            acc[j] += __shfl_xor(acc[j], 16, 64);
            acc[j] += __shfl_xor(acc[j], 32, 64);
        }
        lsum += __shfl_xor(lsum, 16, 64);
        lsum += __shfl_xor(lsum, 32, 64);

        if (t < 16) {
            float inv = 1.f / (lsum + 1e-16f);
            f16x8 hv;
            #pragma unroll
            for (int j = 0; j < 8; j++) hv[j] = (_Float16)(acc[j] * inv);
            *(f16x8*)(hpart + (size_t)dst * HC + head * CH + l16 * 8) = hv;
        }
    }
}

// ======================= D3.5: fold hp1 -> h1c = relu(0.125*sum_heads + b1) ==========
__global__ __launch_bounds__(256) void fold_kernel(const _Float16* __restrict__ hpart,
                                                   const float* __restrict__ b1,
                                                   _Float16* __restrict__ h1c) {
    int t = threadIdx.x;
    int row = blockIdx.x * 16 + (t >> 4);
    int ch0 = (t & 15) * 8;
    if (row >= N_NODES) return;
    f16x8 hvv[8];
    #pragma unroll
    for (int h = 0; h < 8; h++)
        hvv[h] = *(const f16x8*)(hpart + (size_t)row * HC + h * CH + ch0);
    float4 bb0 = *(const float4*)(b1 + ch0);
    float4 bb1 = *(const float4*)(b1 + ch0 + 4);
    float tb[8] = {bb0.x, bb0.y, bb0.z, bb0.w, bb1.x, bb1.y, bb1.z, bb1.w};
    f16x8 o;
    #pragma unroll
    for (int j = 0; j < 8; j++) {
        float s = 0.f;
        #pragma unroll
        for (int h = 0; h < 8; h++) s += (float)hvv[h][j];
        o[j] = (_Float16)fmaxf(fmaf(s, 0.125f, tb[j]), 0.f);
    }
    *(f16x8*)(h1c + (size_t)row * CH + ch0) = o;
}

// ======================= D6: head-mean + relu + final linear =======================
__global__ __launch_bounds__(256) void out_kernel(const _Float16* __restrict__ hpart2,
                                                  const float* __restrict__ b2,
                                                  const float* __restrict__ Wlin,
                                                  const float* __restrict__ blin,
                                                  float* __restrict__ out) {
    int dst = blockIdx.x;
    int t = threadIdx.x;
    __shared__ float hrow[CH];
    if (t < 128) {
        float s = 0.f;
        #pragma unroll
        for (int h = 0; h < 8; h++) s += (float)hpart2[(size_t)dst * HC + h * CH + t];
        hrow[t] = fmaxf(fmaf(s, 0.125f, b2[t]), 0.f);
    }
    __syncthreads();
    if (t < 64) {
        int j = t & 7, p8 = t >> 3;
        float v = 0.f;
        #pragma unroll
        for (int kk = 0; kk < 16; kk++) {
            int k = p8 * 16 + kk;
            v = fmaf(hrow[k], Wlin[k * 8 + j], v);
        }
        v += __shfl_xor(v, 8, 64);
        v += __shfl_xor(v, 16, 64);
        v += __shfl_xor(v, 32, 64);
        if (t < 8) out[(size_t)dst * 8 + t] = v + blin[t];
    }
}

// ======================= fragment-order W conversion (per-thread 16 B chunk) ==========
__device__ __forceinline__ void emit_frag8(const float* __restrict__ W, _Float16* __restrict__ o,
                                           int tid, int KAreal) {
    int f = tid >> 6, l = tid & 63;
    int kq = f >> 6, tile = f & 63;
    int m = l & 15, q = l >> 4;
    int col = tile * 16 + m;
    float v[8];
    #pragma unroll
    for (int j = 0; j < 8; j++) {
        int k = kq * 32 + q * 8 + j;
        v[j] = (k < KAreal) ? W[k * 1024 + col] : 0.f;
    }
    f16x8 hv;
    #pragma unroll
    for (int j = 0; j < 8; j++) hv[j] = (_Float16)v[j];
    *(f16x8*)(o + ((size_t)tid << 3)) = hv;
}

// ======================= D1: init buckets + convert w1 & w2 =======================
__global__ __launch_bounds__(256) void prep_kernel(const float* __restrict__ Wl1, const float* __restrict__ Wr1,
                                                   const float* __restrict__ Wl2, const float* __restrict__ Wr2,
                                                   _Float16* __restrict__ w1l, _Float16* __restrict__ w1r,
                                                   _Float16* __restrict__ w2l, _Float16* __restrict__ w2r,
                                                   int* __restrict__ cnt, int* __restrict__ srcs) {
    int t = threadIdx.x;
    int b = blockIdx.x;
    if (b < 40) {
        int i = b * 256 + t;
        if (i < N_NODES) {
            cnt[i] = 1;               // self loop pre-seeded
            srcs[i << 6] = i;
        }
        return;
    }
    if (b < 72) {
        int tid = (b - 40) * 256 + t;       // 8192 chunks: 4096 per side
        if (tid < 4096) emit_frag8(Wl1, w1l, tid, 16);
        else            emit_frag8(Wr1, w1r, tid - 4096, 16);
        return;
    }
    int tid = (b - 72) * 256 + t;           // 32768 chunks: 16384 per side
    if (tid < 16384) emit_frag8(Wl2, w2l, tid, 128);
    else             emit_frag8(Wr2, w2r, tid - 16384, 128);
}

// ======================= D2: gemm1 ∥ scatter =======================
__global__ __launch_bounds__(256) void d2_kernel(const int* __restrict__ esrc,
                                                 const int* __restrict__ edst,
                                                 int* __restrict__ cnt,
                                                 int* __restrict__ srcs,
                                                 const float* __restrict__ x,
                                                 const _Float16* __restrict__ w1l, const float* __restrict__ bl1,
                                                 const _Float16* __restrict__ w1r, const float* __restrict__ br1,
                                                 _Float16* __restrict__ xlh, _Float16* __restrict__ xrh) {
    __shared__ __align__(16) char smem[17408];
    int b = blockIdx.x;
    if (b < NGEMM) {
        gemm_tile<32, 16, float>(smem, b, x, w1l, bl1, w1r, br1,
                                 xlh, xrh, N_NODES, N_NODES);
    } else {
        int e = (b - NGEMM) * 256 + threadIdx.x;   // NSCAT*256 == N_EDGES
        int d = edst[e];
        int p = atomicAdd(&cnt[d], 1);
        if (p < BCAP) srcs[(d << 6) + p] = esrc[e];
    }
}

// ======================= D4: gemm2 (A = folded fp16 h1c) =======================
__global__ __launch_bounds__(256) void gemm2_kernel(const _Float16* __restrict__ h1c,
                                                    const _Float16* __restrict__ w2l, const float* __restrict__ bl2,
                                                    const _Float16* __restrict__ w2r, const float* __restrict__ br2,
                                                    _Float16* __restrict__ xlh, _Float16* __restrict__ xrh) {
    __shared__ __align__(16) char smem[17408];
    gemm_tile<128, 128, _Float16>(smem, blockIdx.x, h1c, w2l, bl2, w2r, br2,
                                  xlh, xrh, N_NODES, NAG);
}

extern "C" void kernel_launch(void* const* d_in, const int* in_sizes, int n_in,
                              void* d_out, int out_size, void* d_ws, size_t ws_size,
                              hipStream_t stream) {
    const float* x    = (const float*)d_in[0];
    const int*   ei   = (const int*)d_in[1];
    const float* Wl1  = (const float*)d_in[2];
    const float* bl1  = (const float*)d_in[3];
    const float* Wr1  = (const float*)d_in[4];
    const float* br1  = (const float*)d_in[5];
    const float* att1 = (const float*)d_in[6];
    const float* b1   = (const float*)d_in[7];
    const float* Wl2  = (const float*)d_in[8];
    const float* bl2  = (const float*)d_in[9];
    const float* Wr2  = (const float*)d_in[10];
    const float* br2  = (const float*)d_in[11];
    const float* att2 = (const float*)d_in[12];
    const float* b2   = (const float*)d_in[13];
    const float* Wlin = (const float*)d_in[14];
    const float* blin = (const float*)d_in[15];
    float* out = (float*)d_out;

    const int* esrc = ei;
    const int* edst = ei + N_EDGES;

    char* p = (char*)d_ws;
    __half* xlh    = (__half*)p;               p += (size_t)N_NODES * HC * sizeof(__half);
    _Float16* xrh  = (_Float16*)p;             p += (size_t)N_NODES * HC * sizeof(_Float16);
    _Float16* hp1  = (_Float16*)p;             p += (size_t)N_NODES * HC * sizeof(_Float16);
    _Float16* hp2  = (_Float16*)p;             p += (size_t)NAG * HC * sizeof(_Float16);
    _Float16* h1c  = (_Float16*)p;             p += (size_t)N_NODES * CH * sizeof(_Float16);
    _Float16* w1l = (_Float16*)p;              p += 1024 * 32 * sizeof(_Float16);
    _Float16* w1r = (_Float16*)p;              p += 1024 * 32 * sizeof(_Float16);
    _Float16* w2l = (_Float16*)p;              p += 1024 * 128 * sizeof(_Float16);
    _Float16* w2r = (_Float16*)p;              p += 1024 * 128 * sizeof(_Float16);
    int* cnt  = (int*)p;                       p += (size_t)N_NODES * sizeof(int) + 64;
    int* srcs = (int*)p;                       // N_NODES * BCAP

    // D1: init buckets (self-loops) + convert w1/w2 to fragment order
    prep_kernel<<<200, 256, 0, stream>>>(Wl1, Wr1, Wl2, Wr2, w1l, w1r, w2l, w2r, cnt, srcs);
    // D2: layer-1 GEMM ∥ bucket scatter
    d2_kernel<<<NGEMM + NSCAT, 256, 0, stream>>>(esrc, edst, cnt, srcs, x,
                                                 w1l, bl1, w1r, br1,
                                                 (_Float16*)xlh, xrh);
    // D3: layer-1 GAT, one wave per block; head = blockIdx&7 -> XCD slicing
    gat_kernel<<<GATG1 * 8, 64, 0, stream>>>(xlh, xrh, att1, cnt, srcs, hp1,
                                             GATG1, N_NODES);
    // D3.5: fold heads -> h1c (relu + b1)
    fold_kernel<<<(N_NODES + 15) / 16, 256, 0, stream>>>(hp1, b1, h1c);
    // D4: layer-2 GEMM (plain fp16 A)
    gemm2_kernel<<<NGEMM, 256, 0, stream>>>(h1c, w2l, bl2, w2r, br2,
                                            (_Float16*)xlh, xrh);
    // D5: layer-2 GAT (drone dsts only)
    gat_kernel<<<GATG2 * 8, 64, 0, stream>>>(xlh, xrh, att2, cnt, srcs, hp2,
                                             GATG2, NAG);
    // D6: head-mean + relu + b2 + final linear
    out_kernel<<<NAG, 256, 0, stream>>>(hp2, b2, Wlin, blin, out);
}